// Round 5
// baseline (501.007 us; speedup 1.0000x reference)
//
#include <hip/hip_runtime.h>

typedef unsigned short u16;
typedef __attribute__((ext_vector_type(8))) short short8;
typedef __attribute__((ext_vector_type(4))) float floatx4;

#define NN_TOT 135168   // 4096 * 33

// ---- compile-time skeleton (from SKELETON_EDGES, incl. self-loops) ----
static constexpr int NBCNT[33] = {2,2,2,2,2,2,2,1,1,1,1,3,3,2,2,4,4,2,2,2,2,1,1,3,3,2,2,3,3,2,2,2,2};
static constexpr int NBR[33][4] = {
 {1,4,0,0},{0,2,0,0},{1,3,0,0},{2,7,0,0},{0,5,0,0},{4,6,0,0},{5,8,0,0},
 {3,0,0,0},{6,0,0,0},{10,0,0,0},{9,0,0,0},
 {12,13,23,0},{11,14,24,0},{11,15,0,0},{12,16,0,0},
 {13,17,19,21},{14,18,20,22},
 {15,19,0,0},{16,20,0,0},{15,17,0,0},{16,18,0,0},{15,0,0,0},{16,0,0,0},
 {11,24,25,0},{12,23,26,0},{23,27,0,0},{24,28,0,0},
 {25,29,31,0},{26,30,32,0},{27,31,0,0},{28,32,0,0},{29,27,0,0},{30,28,0,0}};
static constexpr float R2 = 0.70710678f, R3 = 0.57735027f, R4 = 0.5f, R5 = 0.44721360f;
static constexpr float DINV[33] = {R3,R3,R3,R3,R3,R3,R3, R2,R2,R2,R2, R4,R4, R3,R3, R5,R5,
                                   R3,R3,R3,R3, R2,R2, R4,R4, R3,R3, R4,R4, R3,R3,R3,R3};

__device__ __forceinline__ float bf2f(u16 u) {
  unsigned int v = ((unsigned int)u) << 16; float f; __builtin_memcpy(&f, &v, 4); return f;
}
__device__ __forceinline__ u16 f2bf(float f) {
  unsigned int u; __builtin_memcpy(&u, &f, 4);
  return (u16)((u + 0x7fffu + ((u >> 16) & 1u)) >> 16);
}
// dtype-flexible input read: isbf ? bf16[i] : f32[i]
__device__ __forceinline__ float ldin(const void* p, int i, int isbf) {
  return isbf ? bf2f(((const u16*)p)[i]) : ((const float*)p)[i];
}
__device__ __forceinline__ void gload_lds16(const u16* g, u16* l) {
  __builtin_amdgcn_global_load_lds((const __attribute__((address_space(1))) unsigned int*)g,
                                   (__attribute__((address_space(3))) unsigned int*)l, 16, 0, 0);
}

// ---- dtype detector ----
__global__ __launch_bounds__(256) void detect_kernel(const u16* __restrict__ x,
                                                     int* __restrict__ flag)
{
  __shared__ int cnt[256];
  const int t = threadIdx.x;
  int c = 0;
  for (int j = 0; j < 16; ++j) {
    u16 u = x[(t*16 + j)*2];
    int e = (u >> 7) & 0xFF;
    c += (e >= 118 && e <= 130) ? 1 : 0;
  }
  cnt[t] = c;
  __syncthreads();
  if (t == 0) {
    int s = 0;
    for (int i = 0; i < 256; ++i) s += cnt[i];
    *flag = (s > 2048) ? 1 : 0;   // 1 = bf16 inputs, 0 = fp32 inputs
  }
}

// ---- W transpose + canonicalize to bf16: Wt[n][k] = W[k][n] ----
__global__ __launch_bounds__(256) void transpose_kernel(const void* __restrict__ w0,
    const void* __restrict__ w1, const void* __restrict__ w2, u16* __restrict__ Wt,
    const int* __restrict__ flag)
{
  const int m = blockIdx.x >> 4;
  const int nb = (blockIdx.x & 15) * 16;
  const void* W = m == 0 ? w0 : (m == 1 ? w1 : w2);
  u16* O = Wt + (size_t)m * 65536;
  const int t = threadIdx.x;
  const int lane = t & 63, wv = t >> 6;
  const int isbf = *flag;
  if (isbf) {
    const u16* Wb = (const u16*)W;
#pragma unroll
    for (int nn = 0; nn < 4; ++nn) {
      const int n = nb + nn*4 + wv;
#pragma unroll
      for (int j = 0; j < 4; ++j) {
        const int k = lane + 64*j;
        O[n*256 + k] = Wb[k*256 + n];
      }
    }
  } else {
    const float* Wf = (const float*)W;
#pragma unroll
    for (int nn = 0; nn < 4; ++nn) {
      const int n = nb + nn*4 + wv;
#pragma unroll
      for (int j = 0; j < 4; ++j) {
        const int k = lane + 64*j;
        O[n*256 + k] = f2bf(Wf[k*256 + n]);
      }
    }
  }
}

// ---- init: wq = wh@wc, bq = bh@wc + bc, zero stat replicas ----
__global__ __launch_bounds__(256) void init_kernel(const void* __restrict__ wh,
    const void* __restrict__ bh, const void* __restrict__ wc, const void* __restrict__ bc,
    float* __restrict__ wq, float* __restrict__ bq, float* __restrict__ repl,
    const int* __restrict__ flag)
{
  const int idx = blockIdx.x*256 + threadIdx.x;
  for (int i = idx; i < 3*64*512; i += 65*256) repl[i] = 0.f;
  const int isbf = *flag;
  const int t = threadIdx.x;
  const int lane = t & 63;
  if (blockIdx.x < 64) {
    const int r = blockIdx.x*4 + (t >> 6);    // wq row, one per wave
    float a0=0.f, a1=0.f, a2=0.f, a3=0.f;
#pragma unroll
    for (int j = 0; j < 4; ++j) {
      const int k = lane + 64*j;
      const float w = ldin(wh, r*256 + k, isbf);
      a0 += w*ldin(wc, k*4+0, isbf); a1 += w*ldin(wc, k*4+1, isbf);
      a2 += w*ldin(wc, k*4+2, isbf); a3 += w*ldin(wc, k*4+3, isbf);
    }
#pragma unroll
    for (int off = 32; off; off >>= 1) {
      a0 += __shfl_xor(a0, off); a1 += __shfl_xor(a1, off);
      a2 += __shfl_xor(a2, off); a3 += __shfl_xor(a3, off);
    }
    if (lane == 0) { wq[r*4+0]=a0; wq[r*4+1]=a1; wq[r*4+2]=a2; wq[r*4+3]=a3; }
  } else if (t < 64) {
    float s0=0.f, s1=0.f, s2=0.f, s3=0.f;
#pragma unroll
    for (int j = 0; j < 4; ++j) {
      const int k = lane + 64*j;
      const float b = ldin(bh, k, isbf);
      s0 += b*ldin(wc, k*4+0, isbf); s1 += b*ldin(wc, k*4+1, isbf);
      s2 += b*ldin(wc, k*4+2, isbf); s3 += b*ldin(wc, k*4+3, isbf);
    }
#pragma unroll
    for (int off = 32; off; off >>= 1) {
      s0 += __shfl_xor(s0, off); s1 += __shfl_xor(s1, off);
      s2 += __shfl_xor(s2, off); s3 += __shfl_xor(s3, off);
    }
    if (lane == 0) {
      bq[0] = s0 + ldin(bc, 0, isbf); bq[1] = s1 + ldin(bc, 1, isbf);
      bq[2] = s2 + ldin(bc, 2, isbf); bq[3] = s3 + ldin(bc, 3, isbf);
    }
  }
}

// ---- FUSED GCN layer: H_out = (Ahat @ act(A_in)) @ W + b, plus BN stats ----
// Commuted form: aggregation is applied to act(A) during LDS staging (legal
// since Ahat mixes rows, W mixes columns). M-tile = 66 rows = 2 whole graphs,
// so all aggregation sources are block-local => in-place (A_in == H_out) safe.
// MFMA runs on 80 rows (5 x 16, rows 66..79 zero-padded).
// ACT==0: act = identity (layer 0; input dtype per flag)
// ACT==1: act = BN-ReLU scale/shift (input bf16)
template<int ACT>
__global__ __launch_bounds__(256, 2) void gcn_kernel(
    const void* __restrict__ Ain, const u16* __restrict__ Bt,
    const float* __restrict__ fscale, const float* __restrict__ fshift,
    const void* __restrict__ bias, u16* __restrict__ Hout,
    float* __restrict__ repl, const int* __restrict__ flag)
{
  __shared__ __align__(16) u16 sA[80*32];    // aggregated act'd A-tile [m][k]
  __shared__ __align__(16) u16 sB[256*32];   // W^T tile [n][k]
  const int tid = threadIdx.x;
  const int lane = tid & 63, wid = tid >> 6;
  const int fr = lane & 15, q = lane >> 4;
  const int n0 = wid * 64;                    // wave's N quarter
  const int isbf = (ACT == 0) ? *flag : 1;
  const size_t row0 = (size_t)blockIdx.x * 66;

  // zero MFMA pad rows 66..79 (never touched in-loop)
  if (tid < 56) *(uint4*)(sA + 66*32 + tid*8) = (uint4){0,0,0,0};

  // staging assignment: threads 0..131 -> (row, 16-col half)
  const int sr = tid >> 1;                    // candidate row 0..127
  const int sc0 = (tid & 1) * 16;
  const bool stg = (sr < 66);
  int srcs[5]; float wts[5];
  {
    const int rmc = (sr < 33) ? sr : ((sr < 66) ? sr - 33 : 0);
    const int rbase = (sr < 33) ? 0 : 33;
    const float di = DINV[rmc];
    srcs[0] = rbase + rmc; wts[0] = di * di;
#pragma unroll
    for (int j = 0; j < 4; ++j) {
      if (j < NBCNT[rmc]) { const int s = NBR[rmc][j]; srcs[j+1] = rbase + s; wts[j+1] = di * DINV[s]; }
      else { srcs[j+1] = rbase; wts[j+1] = 0.f; }
    }
  }

  floatx4 acc[5][4];
#pragma unroll
  for (int mt = 0; mt < 5; ++mt)
#pragma unroll
    for (int nt = 0; nt < 4; ++nt) acc[mt][nt] = (floatx4){0.f,0.f,0.f,0.f};

  for (int kc = 0; kc < 8; ++kc) {
    const int k0 = kc * 32;
    __syncthreads();
    // B staging via async LDS-DMA (issues early, overlaps A staging VALU)
#pragma unroll
    for (int i = 0; i < 4; ++i)
      gload_lds16(Bt + (wid*64 + i*16 + (lane>>2))*256 + k0 + (lane&3)*8,
                  sB + (wid*64 + i*16)*32);
    // A staging: G[r][c] = sum_j w_j * act(A[src_j][c])
    if (stg) {
      float av[16];
#pragma unroll
      for (int e = 0; e < 16; ++e) av[e] = 0.f;
      float scv[16], shv[16];
      if (ACT == 1) {
#pragma unroll
        for (int e = 0; e < 16; ++e) { scv[e] = fscale[k0 + sc0 + e]; shv[e] = fshift[k0 + sc0 + e]; }
      }
      if (isbf) {
        const u16* Ab = (const u16*)Ain;
#pragma unroll
        for (int j = 0; j < 5; ++j) {
          const u16* sp = Ab + (row0 + srcs[j])*256 + k0 + sc0;
          uint4 p0 = *(const uint4*)sp;
          uint4 p1 = *(const uint4*)(sp + 8);
          const u16* u0 = (const u16*)&p0;
          const u16* u1 = (const u16*)&p1;
          const float w = wts[j];
#pragma unroll
          for (int e = 0; e < 8; ++e) {
            float f0 = bf2f(u0[e]), f1 = bf2f(u1[e]);
            if (ACT == 1) {
              f0 = fmaxf(0.f, fmaf(f0, scv[e], shv[e]));
              f1 = fmaxf(0.f, fmaf(f1, scv[e+8], shv[e+8]));
            }
            av[e] += w * f0; av[e+8] += w * f1;
          }
        }
      } else {
        const float* Af = (const float*)Ain;
#pragma unroll
        for (int j = 0; j < 5; ++j) {
          const float* sp = Af + (row0 + srcs[j])*256 + k0 + sc0;
          const float w = wts[j];
#pragma unroll
          for (int v = 0; v < 4; ++v) {
            float4 p = *(const float4*)(sp + v*4);
            av[v*4+0] += w * p.x; av[v*4+1] += w * p.y;
            av[v*4+2] += w * p.z; av[v*4+3] += w * p.w;
          }
        }
      }
      u16 ov[16];
#pragma unroll
      for (int e = 0; e < 16; ++e) ov[e] = f2bf(av[e]);
      *(uint4*)(sA + sr*32 + sc0)     = *(const uint4*)(ov);
      *(uint4*)(sA + sr*32 + sc0 + 8) = *(const uint4*)(ov + 8);
    }
    __syncthreads();

    short8 a[5], b[4];
#pragma unroll
    for (int mt = 0; mt < 5; ++mt) a[mt] = *(const short8*)(sA + (mt*16 + fr)*32 + q*8);
#pragma unroll
    for (int nt = 0; nt < 4; ++nt) b[nt] = *(const short8*)(sB + (n0 + nt*16 + fr)*32 + q*8);
#pragma unroll
    for (int mt = 0; mt < 5; ++mt)
#pragma unroll
      for (int nt = 0; nt < 4; ++nt)
        acc[mt][nt] = __builtin_amdgcn_mfma_f32_16x16x32_bf16(a[mt], b[nt], acc[mt][nt], 0, 0, 0);
  }

  // epilogue: +bias, write rows<66, per-channel stats (s1,s2) -> replicas
  float bv[4], s1[4], s2[4];
#pragma unroll
  for (int nt = 0; nt < 4; ++nt) {
    bv[nt] = ldin(bias, n0 + nt*16 + fr, *flag);
    s1[nt] = 0.f; s2[nt] = 0.f;
  }
#pragma unroll
  for (int mt = 0; mt < 5; ++mt)
#pragma unroll
    for (int nt = 0; nt < 4; ++nt)
#pragma unroll
      for (int rr = 0; rr < 4; ++rr) {
        const int row = mt*16 + q*4 + rr;
        if (row < 66) {
          const float h = acc[mt][nt][rr] + bv[nt];
          Hout[(row0 + row)*256 + n0 + nt*16 + fr] = f2bf(h);
          s1[nt] += h; s2[nt] += h*h;
        }
      }
#pragma unroll
  for (int nt = 0; nt < 4; ++nt) {
    s1[nt] += __shfl_xor(s1[nt], 16); s1[nt] += __shfl_xor(s1[nt], 32);
    s2[nt] += __shfl_xor(s2[nt], 16); s2[nt] += __shfl_xor(s2[nt], 32);
  }
  if (lane < 16) {
    float* r1 = repl + (size_t)(blockIdx.x & 63) * 512;
#pragma unroll
    for (int nt = 0; nt < 4; ++nt) {
      atomicAdd(r1 + n0 + nt*16 + fr, s1[nt]);
      atomicAdd(r1 + 256 + n0 + nt*16 + fr, s2[nt]);
    }
  }
}

// ---- finalize BN stats -> scale/shift ----
__global__ __launch_bounds__(256) void statfin_kernel(const float* __restrict__ repl,
    const void* __restrict__ gamma, const void* __restrict__ beta, float* __restrict__ fs,
    const int* __restrict__ flag)
{
  const int c = threadIdx.x;
  const int isbf = *flag;
  float s1 = 0.f, s2 = 0.f;
  for (int r = 0; r < 64; ++r) { s1 += repl[r*512 + c]; s2 += repl[r*512 + 256 + c]; }
  const float inv = 1.f / (float)NN_TOT;
  const float mu = s1 * inv;
  const float var = s2 * inv - mu*mu;
  const float rs = rsqrtf(var + 1e-5f);
  const float sc = rs * ldin(gamma, c, isbf);
  fs[c] = sc;
  fs[256 + c] = ldin(beta, c, isbf) - mu * sc;
}

// ---- fused layer3 + mean-pool + classifier ----
__global__ __launch_bounds__(256) void final_kernel(const u16* __restrict__ H,
    const float* __restrict__ fs, const float* __restrict__ wq,
    const float* __restrict__ bq, void* __restrict__ outp,
    const int* __restrict__ flag)
{
  const int g = blockIdx.x, c = threadIdx.x;
  const int isbf = *flag;
  const float sc = fs[c], sh = fs[256 + c];
  const u16* hg = H + (size_t)g * (33*256);
  float v = 0.f;
#pragma unroll
  for (int s = 0; s < 33; ++s) {
    float a = DINV[s];
#pragma unroll
    for (int i = 0; i < NBCNT[s]; ++i) a += DINV[NBR[s][i]];
    const float w = DINV[s] * a * (1.f/33.f);   // column-sum of Ahat / 33
    float x = bf2f(hg[s*256 + c]);
    x = fmaxf(0.f, fmaf(x, sc, sh));
    v += w * x;
  }
  float p0 = v*wq[c*4+0], p1 = v*wq[c*4+1], p2 = v*wq[c*4+2], p3 = v*wq[c*4+3];
#pragma unroll
  for (int off = 32; off; off >>= 1) {
    p0 += __shfl_xor(p0, off);
    p1 += __shfl_xor(p1, off);
    p2 += __shfl_xor(p2, off);
    p3 += __shfl_xor(p3, off);
  }
  __shared__ float sred[4][4];
  const int lane = c & 63, wid = c >> 6;
  if (lane == 0) { sred[wid][0]=p0; sred[wid][1]=p1; sred[wid][2]=p2; sred[wid][3]=p3; }
  __syncthreads();
  if (c < 4) {
    float r = sred[0][c] + sred[1][c] + sred[2][c] + sred[3][c] + bq[c];
    if (isbf) ((u16*)outp)[(size_t)g*4 + c] = f2bf(r);
    else      ((float*)outp)[(size_t)g*4 + c] = r;
  }
}

extern "C" void kernel_launch(void* const* d_in, const int* in_sizes, int n_in,
                              void* d_out, int out_size, void* d_ws, size_t ws_size,
                              hipStream_t stream)
{
  const void* x   = d_in[0];
  const void* w0  = d_in[1];
  const void* b0  = d_in[2];
  const void* g0  = d_in[3];
  const void* be0 = d_in[4];
  const void* w1  = d_in[5];
  const void* b1  = d_in[6];
  const void* g1  = d_in[7];
  const void* be1 = d_in[8];
  const void* w2  = d_in[9];
  const void* b2  = d_in[10];
  const void* g2  = d_in[11];
  const void* be2 = d_in[12];
  const void* wh  = d_in[13];
  const void* bh  = d_in[14];
  const void* wc  = d_in[15];
  const void* bc  = d_in[16];

  // Workspace: 66.8 MB total.
  char* ws = (char*)d_ws;
  float* wq   = (float*)(ws + 0);          // 1024 f
  float* bq   = (float*)(ws + 4096);       // 4 f
  float* fs   = (float*)(ws + 4608);       // 3 * 512 f
  int*   flag = (int*)  (ws + 12288);      // dtype flag
  float* repl = (float*)(ws + 16384);      // 3 * 64 * 512 f
  u16*   Wt   = (u16*)  (ws + 409600);     // 3 * 65536 bf16
  u16*   A    = (u16*)  (ws + 802816);     // 135168*256 bf16
  (void)in_sizes; (void)n_in; (void)out_size; (void)ws_size;

  detect_kernel<<<1, 256, 0, stream>>>((const u16*)x, flag);
  transpose_kernel<<<48, 256, 0, stream>>>(w0, w1, w2, Wt, flag);
  init_kernel<<<65, 256, 0, stream>>>(wh, bh, wc, bc, wq, bq, repl, flag);

  // layer 0: H0 = (Ahat @ x) @ W0 + b0
  gcn_kernel<0><<<2048, 256, 0, stream>>>(x, Wt, nullptr, nullptr, b0, A, repl, flag);
  statfin_kernel<<<1, 256, 0, stream>>>(repl, g0, be0, fs, flag);
  // layer 1 (in-place): H1 = (Ahat @ bnrelu(H0)) @ W1 + b1
  gcn_kernel<1><<<2048, 256, 0, stream>>>(A, Wt + 65536, fs, fs + 256, b1, A, repl + 32768, flag);
  statfin_kernel<<<1, 256, 0, stream>>>(repl + 32768, g1, be1, fs + 512, flag);
  // layer 2 (in-place)
  gcn_kernel<1><<<2048, 256, 0, stream>>>(A, Wt + 131072, fs + 512, fs + 768, b2, A, repl + 65536, flag);
  statfin_kernel<<<1, 256, 0, stream>>>(repl + 65536, g2, be2, fs + 1024, flag);
  // layer 3 + pool + classifier (folded)
  final_kernel<<<4096, 256, 0, stream>>>(A, fs + 1024, wq, bq, d_out, flag);
}